// Round 4
// baseline (1992.820 us; speedup 1.0000x reference)
//
#include <hip/hip_runtime.h>
#include <cstdint>

// ---------------------------------------------------------------------------
// TempFuseDilateAttention on MI355X — baseline (correctness-first, f32)
//
// Shapes: q [2,200,200,128] f32, x [2,2,200,200,128] f32,
//         kv_weight [256,128], proj_weight [128,128], proj_bias [128].
// Derivations (re-audited r2/r3): all torch reshapes are flat reinterprets;
//   - head i: K = conv(x[bl][t=0]) chans [128i,+128), V = conv(x[bl][t=1])
//   - gather: F=(cc2*9+kk2)*40000+p -> digits (uc,kk,uh,uw) radix (.,9,200,128)
//     w2=uh+(ik-1)*dil, c2=uw+(jk-1)*dil (zero pad OOB), value at linear
//     idx = uc*25600 + w2*128 + c2 within the head's half-slice (conv [oo][p]).
//   - r3 analysis: idx = wave-uniform base + pr (pr=p%1600) -> lane-contiguous.
//     (strength-reduction deferred until counters confirm attn addressing cost)
// ---------------------------------------------------------------------------

#define HWQ 40000u
#define SCALE_F 0.17677669529663687f   // 32^-0.5

// ---------------- 1x1 conv (half: 128 output channels for one head) --------
// KVh[n][oo][p] = sum_c x[n][p][c] * kvw[ihead*128+oo][c]
// grid (625 p-tiles, 2 oo-tiles, 4 n), block 256. Tile 64x64, reg tile 4x4.
__global__ __launch_bounds__(256) void conv1x1_kernel(
    const float* __restrict__ x, const float* __restrict__ kvw,
    float* __restrict__ kvh, int ihead)
{
    __shared__ float Wt[64][132];
    __shared__ float Xt[64][132];
    const int tid = threadIdx.x;
    const int n   = blockIdx.z;
    const int oo0 = blockIdx.y * 64;
    const int p0  = blockIdx.x * 64;

    // stage tiles: 64 rows x 128 c, as 2048 float4s (8 per thread)
    #pragma unroll
    for (int it = 0; it < 8; ++it) {
        int idx = tid + it * 256;
        int row = idx >> 5;
        int cv  = idx & 31;
        float4 wv = *(const float4*)(kvw + (size_t)(ihead * 128 + oo0 + row) * 128 + cv * 4);
        *(float4*)&Wt[row][cv * 4] = wv;
        float4 xv = *(const float4*)(x + ((size_t)n * HWQ + (size_t)(p0 + row)) * 128 + cv * 4);
        *(float4*)&Xt[row][cv * 4] = xv;
    }
    __syncthreads();

    const int ty = tid >> 4;   // 0..15 -> oo = ty*4 + i
    const int tx = tid & 15;   // 0..15 -> p  = tx + 16*j   (stride-16: bank-friendly)
    float acc[4][4];
    #pragma unroll
    for (int i = 0; i < 4; ++i)
        #pragma unroll
        for (int j = 0; j < 4; ++j) acc[i][j] = 0.0f;

    #pragma unroll
    for (int c4 = 0; c4 < 32; ++c4) {
        float4 wv[4], xv[4];
        #pragma unroll
        for (int i = 0; i < 4; ++i) wv[i] = *(float4*)&Wt[ty * 4 + i][c4 * 4];
        #pragma unroll
        for (int j = 0; j < 4; ++j) xv[j] = *(float4*)&Xt[tx + 16 * j][c4 * 4];
        #pragma unroll
        for (int i = 0; i < 4; ++i)
            #pragma unroll
            for (int j = 0; j < 4; ++j)
                acc[i][j] += wv[i].x * xv[j].x + wv[i].y * xv[j].y
                           + wv[i].z * xv[j].z + wv[i].w * xv[j].w;
    }

    #pragma unroll
    for (int i = 0; i < 4; ++i)
        #pragma unroll
        for (int j = 0; j < 4; ++j)
            kvh[((size_t)n * 128 + (size_t)(oo0 + ty * 4 + i)) * HWQ + (size_t)(p0 + tx + 16 * j)]
                = acc[i][j];
}

// ---------------- dilate attention gather ----------------------------------
__device__ __forceinline__ float kv_gather(const float* __restrict__ base,
                                           uint32_t F, int dil)
{
    uint32_t qq = F / 25600u;            // = uc*9 + kk   (< 1800)
    uint32_t r2 = F - qq * 25600u;
    uint32_t uc = qq / 9u;
    uint32_t kk = qq - uc * 9u;
    uint32_t uh = r2 >> 7u;              // /128  -> unfold-H index (actual w)
    uint32_t uw = r2 & 127u;             // %128  -> unfold-W index (actual c)
    uint32_t ik = (kk * 11u) >> 5u;      // kk/3 for kk<9
    uint32_t jk = kk - ik * 3u;
    int w2 = (int)uh + ((int)ik - 1) * dil;
    int c2 = (int)uw + ((int)jk - 1) * dil;
    bool ok = ((uint32_t)w2 < 200u) && ((uint32_t)c2 < 128u);
    uint32_t idx = uc * 25600u + (uint32_t)(w2 * 128 + c2);
    float v = base[ok ? idx : 0u];
    return ok ? v : 0.0f;
}

// block 256 = 4 nh-waves x 64 consecutive p; grid (625, 2=b)
__global__ __launch_bounds__(256) void attn_kernel(
    const float* __restrict__ Qin, const float* __restrict__ KVh,
    float* __restrict__ Qout, int dil)
{
    const uint32_t b   = blockIdx.y;
    const uint32_t pl  = threadIdx.x & 63u;
    const uint32_t nh  = threadIdx.x >> 6u;       // wave-uniform
    const uint32_t p   = blockIdx.x * 64u + pl;
    const uint32_t cc0 = nh * 32u;

    const float* __restrict__ Qb = Qin + (size_t)b * 5120000u;
    const float* __restrict__ Kb = KVh + (size_t)(2u * b)      * 5120000u;
    const float* __restrict__ Vb = KVh + (size_t)(2u * b + 1u) * 5120000u;

    float qv[32];
    #pragma unroll
    for (int j = 0; j < 32; ++j) qv[j] = Qb[(size_t)(cc0 + j) * HWQ + p];

    // scores s[kk2] = sum_hd2 q * ku   (fully unrolled: arrays stay in regs)
    float s[9];
    #pragma unroll
    for (int k2 = 0; k2 < 9; ++k2) s[k2] = 0.0f;
    #pragma unroll
    for (int j = 0; j < 32; ++j) {
        const uint32_t Fb = (cc0 + (uint32_t)j) * 9u;
        #pragma unroll
        for (int k2 = 0; k2 < 9; ++k2) {
            float kval = kv_gather(Kb, (Fb + (uint32_t)k2) * HWQ + p, dil);
            s[k2] = fmaf(qv[j], kval, s[k2]);
        }
    }

    // softmax over 9 (scale folded into exp)
    float m = s[0];
    #pragma unroll
    for (int k2 = 1; k2 < 9; ++k2) m = fmaxf(m, s[k2]);
    float a[9];
    float sum = 0.0f;
    #pragma unroll
    for (int k2 = 0; k2 < 9; ++k2) {
        a[k2] = __expf((s[k2] - m) * SCALE_F);
        sum += a[k2];
    }
    const float inv = 1.0f / sum;

    // out[hd] = (sum_kk2 a * vu) * inv
    float ov[32];
    #pragma unroll
    for (int hd = 0; hd < 32; ++hd) {
        float acc = 0.0f;
        const uint32_t Fb = (cc0 + (uint32_t)hd) * 9u;
        #pragma unroll
        for (int k2 = 0; k2 < 9; ++k2)
            acc = fmaf(a[k2], kv_gather(Vb, (Fb + (uint32_t)k2) * HWQ + p, dil), acc);
        ov[hd] = acc * inv;
    }

    float* dst = Qout + (size_t)b * 5120000u + (size_t)p * 128u + cc0;
    #pragma unroll
    for (int j2 = 0; j2 < 8; ++j2) {
        float4 v4 = make_float4(ov[4 * j2], ov[4 * j2 + 1], ov[4 * j2 + 2], ov[4 * j2 + 3]);
        *(float4*)(dst + 4 * j2) = v4;
    }
}

// ---------------- final projection (in-place safe) --------------------------
// out[b,p,co] = sum_c qin[b,p,c]*pw[co,c] + pb[co]
// grid (625, 2), block 256. Block covers all 128 co x 64 p; stages its own
// p-rows in LDS before any store -> in-place on d_out is race-free.
__global__ __launch_bounds__(256) void proj_kernel(
    const float* qin, const float* __restrict__ pw,
    const float* __restrict__ pb, float* outp)
{
    __shared__ float Xt[64][132];
    __shared__ float bias[128];
    const int tid = threadIdx.x;
    const int b   = blockIdx.y;
    const int p0  = blockIdx.x * 64;
    const size_t base = (size_t)b * 5120000u + (size_t)p0 * 128u;

    #pragma unroll
    for (int it = 0; it < 8; ++it) {
        int idx = tid + it * 256;
        int row = idx >> 5;
        int cv  = idx & 31;
        float4 v = *(const float4*)(qin + base + (size_t)row * 128 + cv * 4);
        *(float4*)&Xt[row][cv * 4] = v;
    }
    if (tid < 32) {
        float4 t = *(const float4*)(pb + tid * 4);
        *(float4*)&bias[tid * 4] = t;
    }
    __syncthreads();

    const int ty = tid >> 4;   // co = ty*8 + i
    const int tx = tid & 15;   // p  = tx + 16*j
    float acc[8][4];
    #pragma unroll
    for (int i = 0; i < 8; ++i)
        #pragma unroll
        for (int j = 0; j < 4; ++j) acc[i][j] = 0.0f;

    #pragma unroll
    for (int c4 = 0; c4 < 32; ++c4) {
        float4 xv[4], wv[8];
        #pragma unroll
        for (int j = 0; j < 4; ++j) xv[j] = *(float4*)&Xt[tx + 16 * j][c4 * 4];
        #pragma unroll
        for (int i = 0; i < 8; ++i)
            wv[i] = *(const float4*)(pw + (size_t)(ty * 8 + i) * 128 + c4 * 4);
        #pragma unroll
        for (int i = 0; i < 8; ++i)
            #pragma unroll
            for (int j = 0; j < 4; ++j)
                acc[i][j] += wv[i].x * xv[j].x + wv[i].y * xv[j].y
                           + wv[i].z * xv[j].z + wv[i].w * xv[j].w;
    }

    #pragma unroll
    for (int j = 0; j < 4; ++j) {
        float* drow = outp + base + (size_t)(tx + 16 * j) * 128 + ty * 8;
        float4 lo = make_float4(acc[0][j] + bias[ty * 8 + 0], acc[1][j] + bias[ty * 8 + 1],
                                acc[2][j] + bias[ty * 8 + 2], acc[3][j] + bias[ty * 8 + 3]);
        float4 hi = make_float4(acc[4][j] + bias[ty * 8 + 4], acc[5][j] + bias[ty * 8 + 5],
                                acc[6][j] + bias[ty * 8 + 6], acc[7][j] + bias[ty * 8 + 7]);
        *(float4*)(drow)     = lo;
        *(float4*)(drow + 4) = hi;
    }
}

// ---------------------------------------------------------------------------
extern "C" void kernel_launch(void* const* d_in, const int* in_sizes, int n_in,
                              void* d_out, int out_size, void* d_ws, size_t ws_size,
                              hipStream_t stream)
{
    const float* q   = (const float*)d_in[0];   // [2,200,200,128]
    const float* x   = (const float*)d_in[1];   // [2,2,200,200,128]
    const float* kvw = (const float*)d_in[2];   // [256,128]
    const float* pw  = (const float*)d_in[3];   // [128,128]
    const float* pb  = (const float*)d_in[4];   // [128]
    float* out = (float*)d_out;                 // [2,200,200,128]

    // ws layout: KVh [4][128][40000] f32 = 81,920,000 B ; q1 = 40,960,000 B
    const size_t KVH_BYTES = 81920000u;
    const size_t Q1_BYTES  = 40960000u;
    if (ws_size < KVH_BYTES + Q1_BYTES) return;   // insufficient scratch
    float* kvh = (float*)d_ws;
    float* q1  = (float*)((char*)d_ws + KVH_BYTES);

    dim3 blk(256);
    dim3 cgrid(625, 2, 4);   // p-tiles, oo-tiles, n
    dim3 agrid(625, 2);      // p-tiles, b
    dim3 pgrid(625, 2);

    // head 0 (dil=1)
    conv1x1_kernel<<<cgrid, blk, 0, stream>>>(x, kvw, kvh, 0);
    attn_kernel  <<<agrid, blk, 0, stream>>>(q, kvh, q1, 1);
    // head 1 (dil=2)
    conv1x1_kernel<<<cgrid, blk, 0, stream>>>(x, kvw, kvh, 1);
    attn_kernel  <<<agrid, blk, 0, stream>>>(q1, kvh, out, 2);
    // projection, in-place on d_out
    proj_kernel  <<<pgrid, blk, 0, stream>>>(out, pw, pb, out);
}